// Round 12
// baseline (351.605 us; speedup 1.0000x reference)
//
#include <hip/hip_runtime.h>
#include <hip/hip_bf16.h>
#include <stdint.h>
#include <math.h>

#define SEQ_LEN 256
#define BATCH   16384

typedef _Float16 half8  __attribute__((ext_vector_type(8)));
typedef _Float16 half2t __attribute__((ext_vector_type(2)));
typedef __attribute__((ext_vector_type(4))) float    floatx4;
typedef __attribute__((ext_vector_type(4))) uint32_t uint4v;
typedef __attribute__((ext_vector_type(2))) float    float2v;

__device__ __forceinline__ uint32_t pkh(float a, float b){
    return __builtin_bit_cast(uint32_t, __builtin_amdgcn_cvt_pkrtz(a, b));
}
__device__ __forceinline__ float h16lo(uint32_t p){
    return (float)__builtin_bit_cast(half2t, p)[0];
}
__device__ __forceinline__ float h16hi(uint32_t p){
    return (float)__builtin_bit_cast(half2t, p)[1];
}
__device__ __forceinline__ half8 ashfrag(uint4v u){ return __builtin_bit_cast(half8, u); }
#define MFMA_H(A,B,C) __builtin_amdgcn_mfma_f32_16x16x32_f16((A),(B),(C),0,0,0)

// 2-wave neuron-split version of the r11-verified f16 double-split rollout.
// Wave 0 owns output tiles t=0,1 (j 0..31); wave 1 owns t=2,3 (j 32..49+bias).
// Each wave computes its half of every layer over the FULL K range; at layer
// boundaries the packed H-fragment halves are swapped via LDS (+barrier).
// All packing / k-map (kk=16(v>>1)+4phi+2(v&1)+q) / C-D (row=4phi+reg) /
// store formulas are byte-identical to r8-r11's HW-verified ones; only the
// work assignment changes -> bit-identical numerics, 2 waves/SIMD occupancy.
__global__ __launch_bounds__(128, 2) void mbrl_mfma2(
    const float* __restrict__ state0, const float* __restrict__ pstate0,
    const float* __restrict__ target,
    const float* __restrict__ W1, const float* __restrict__ b1,
    const float* __restrict__ W2, const float* __restrict__ b2,
    const float* __restrict__ W3, const float* __restrict__ b3,
    const float* __restrict__ W4, const float* __restrict__ b4,
    float* __restrict__ out)
{
    const int tid  = threadIdx.x;
    const int wid  = tid >> 6;         // wave 0/1 within block
    const int lane = tid & 63;
    const int c16  = lane & 15;
    const int phi  = lane >> 4;
    const int rowg = (int)blockIdx.x * 16 + c16;

    __shared__ __align__(16) uint4v  xA[2][2][64];   // L1->L2 H-frag exchange
    __shared__ __align__(16) uint4v  xB[2][2][64];   // L2->L3
    __shared__ __align__(16) float2v zxch[2][64];    // L4 partial-z exchange

    // ---------------- Layer-1 A tiles (own 2 chains: tg = 2*wid + tl) ----------------
    half8 P1[2], Q1[2];
#pragma unroll
    for (int tl = 0; tl < 2; ++tl){
        const int j = 16*(2*wid + tl) + c16;
        uint4v uP, uQ;
#pragma unroll
        for (int v = 0; v < 4; ++v){
            float pP[2], pQ[2];
#pragma unroll
            for (int q = 0; q < 2; ++q){
                const int kk = 16*(v>>1) + 4*phi + 2*(v&1) + q;
                float w = 0.f;
                if (j < 50){
                    if (kk < 12)                  w = W1[kk*50 + j];
                    else if (kk == 12)            w = b1[j];
                    else if (kk >= 16 && kk < 28) w = W1[(kk-16)*50 + j];
                }
                float s0 = (float)(_Float16)w;
                pP[q] = s0; pQ[q] = w - s0;
            }
            uP[v] = pkh(pP[0], pP[1]);
            uQ[v] = pkh(pQ[0], pQ[1]);
        }
        P1[tl] = ashfrag(uP); Q1[tl] = ashfrag(uQ);
    }

    // ---------------- Layer-2/3 A tiles for own chains ----------------
    half8 A2[2][2][2], A3[2][2][2];    // [split][tl][kt]
#pragma unroll
    for (int tl = 0; tl < 2; ++tl){
        const int j = 16*(2*wid + tl) + c16;
#pragma unroll
        for (int kt = 0; kt < 2; ++kt){
            uint4v u2[2], u3[2];
#pragma unroll
            for (int v = 0; v < 4; ++v){
                float p2[2][2], p3[2][2];
#pragma unroll
                for (int q = 0; q < 2; ++q){
                    const int kk = 32*kt + 16*(v>>1) + 4*phi + 2*(v&1) + q;
                    float w2v = 0.f, w3v = 0.f;
                    if (j < 50){
                        if (kk < 50){ w2v = W2[kk*50 + j]; w3v = W3[kk*50 + j]; }
                        else if (kk == 50){ w2v = b2[j]; w3v = b3[j]; }
                    }
                    float a0  = (float)(_Float16)w2v;
                    float c0s = (float)(_Float16)w3v;
                    p2[0][q] = a0;  p2[1][q] = w2v - a0;
                    p3[0][q] = c0s; p3[1][q] = w3v - c0s;
                }
#pragma unroll
                for (int s = 0; s < 2; ++s){
                    u2[s][v] = pkh(p2[s][0], p2[s][1]);
                    u3[s][v] = pkh(p3[s][0], p3[s][1]);
                }
            }
#pragma unroll
            for (int s = 0; s < 2; ++s){
                A2[s][tl][kt] = ashfrag(u2[s]); A3[s][tl][kt] = ashfrag(u3[s]);
            }
        }
    }

    // ---------------- Layer-4 per-lane f32 weights (own 8 j-values) ----------------
    float w4a[8], w4b[8];
#pragma unroll
    for (int tl = 0; tl < 2; ++tl)
#pragma unroll
        for (int r = 0; r < 4; ++r){
            const int j = 32*wid + 16*tl + 4*phi + r;
            w4a[4*tl+r] = (j < 50) ? W4[j*2 + 0] : 0.f;
            w4b[4*tl+r] = (j < 50) ? W4[j*2 + 1] : 0.f;
        }
    const float b40 = b4[0], b41 = b4[1];

    // ---------------- per-row state (duplicated across lanes/waves) ----------------
    float ps[6], ss[6], tg[6];
#pragma unroll
    for (int i = 0; i < 6; ++i){
        ps[i] = pstate0[(size_t)rowg*6 + i];
        ss[i] = state0 [(size_t)rowg*6 + i];
        tg[i] = target [(size_t)rowg*6 + i];
    }

    const float DT  = 0.05f;
    const float PI4 = 0.78539816339744830962f;
    const floatx4 z4 = {0.f,0.f,0.f,0.f};
    const uint32_t ONE_H = 0x00003C00u;    // (f16 1.0, f16 0.0)

    float* uout = out + (size_t)rowg * 2;
    float* sout = out + (size_t)SEQ_LEN * BATCH * 2 + (size_t)rowg * 6;

#define SPLITH(HA,HB,PK0,PK1) do{                                      \
        PK0 = pkh((HA),(HB));                                          \
        float _a = h16lo(PK0), _b = h16hi(PK0);                        \
        PK1 = pkh((HA)-_a, (HB)-_b);                                   \
    }while(0)

    // pack this wave's half of the H fragments (r11 MKH word layout)
#define PACKH(CA,CB,U0,U1) do{                                                           \
        { float ha=fmaxf(CA[0],0.f), hb=fmaxf(CA[1],0.f); SPLITH(ha,hb,U0[0],U1[0]); }   \
        { float ha=fmaxf(CA[2],0.f), hb=fmaxf(CA[3],0.f); SPLITH(ha,hb,U0[1],U1[1]); }   \
        { float ha=fmaxf(CB[0],0.f), hb=fmaxf(CB[1],0.f); SPLITH(ha,hb,U0[2],U1[2]); }   \
        { float ha=fmaxf(CB[2],0.f), hb=fmaxf(CB[3],0.f); SPLITH(ha,hb,U0[3],U1[3]); }   \
        if (wid == 1 && phi == 0){ U0[3] = ONE_H; U1[3] = 0u; }  /* h[50]=1,h[51]=0 */   \
    }while(0)

    // exchange own (u0,u1) through region R; build full H frags
#define XCHG(R)  do{                                                    \
        R[wid][0][lane] = u0; R[wid][1][lane] = u1;                     \
        __syncthreads();                                                \
        uint4v o0 = R[wid^1][0][lane], o1 = R[wid^1][1][lane];          \
        if (wid == 0){ H0a=ashfrag(u0); H1a=ashfrag(u1);                \
                       H0b=ashfrag(o0); H1b=ashfrag(o1); }              \
        else         { H0a=ashfrag(o0); H1a=ashfrag(o1);                \
                       H0b=ashfrag(u0); H1b=ashfrag(u1); }              \
    }while(0)

    // hidden layer, own 2 chains, 12 MFMAs (r11 term/accumulation order)
#define HID(A)                                                              \
        ca=MFMA_H(A[0][0][0],H0a,z4); cb=MFMA_H(A[0][1][0],H0a,z4);         \
        ca=MFMA_H(A[0][0][1],H0b,ca); cb=MFMA_H(A[0][1][1],H0b,cb);         \
        ca=MFMA_H(A[0][0][0],H1a,ca); cb=MFMA_H(A[0][1][0],H1a,cb);         \
        ca=MFMA_H(A[0][0][1],H1b,ca); cb=MFMA_H(A[0][1][1],H1b,cb);         \
        ca=MFMA_H(A[1][0][0],H0a,ca); cb=MFMA_H(A[1][1][0],H0a,cb);         \
        ca=MFMA_H(A[1][0][1],H0b,ca); cb=MFMA_H(A[1][1][1],H0b,cb);

    for (int t = 0; t < SEQ_LEN; ++t){
        // ---- X build (identical in both waves) ----
        float X0=ps[0]-tg[0], X1=ps[1]-tg[1], X2=ps[2]-tg[2];
        float X3=ps[3]-tg[3], X4=ps[4]-tg[4], X5=ps[5]-tg[5];
        float X6=ss[0]-tg[0], X7=ss[1]-tg[1], X8=ss[2]-tg[2];
        float X9=ss[3]-tg[3], X10=ss[4]-tg[4], X11=ss[5]-tg[5];
        float xs0 = (phi==0)?X0:(phi==1)?X4:(phi==2)?X8 :0.f;
        float xs1 = (phi==0)?X1:(phi==1)?X5:(phi==2)?X9 :0.f;
        float xs2 = (phi==0)?X2:(phi==1)?X6:(phi==2)?X10:0.f;
        float xs3 = (phi==0)?X3:(phi==1)?X7:(phi==2)?X11:0.f;
        uint32_t pH01,pL01,pH23,pL23;
        SPLITH(xs0,xs1,pH01,pL01);
        SPLITH(xs2,xs3,pH23,pL23);
        uint4v f1;
        f1[0] = (phi==3) ? ONE_H : pH01;   // phi==3: all other words are 0 naturally
        f1[1] = pH23;
        f1[2] = pL01;
        f1[3] = pL23;
        const half8 F1 = ashfrag(f1);

        // ---- layer 1: own 2 chains (4 MFMAs) ----
        floatx4 ca, cb;
        ca=MFMA_H(P1[0],F1,z4); cb=MFMA_H(P1[1],F1,z4);
        ca=MFMA_H(Q1[0],F1,ca); cb=MFMA_H(Q1[1],F1,cb);

        half8 H0a,H0b,H1a,H1b;
        uint4v u0, u1;
        PACKH(ca,cb,u0,u1);
        XCHG(xA);

        // ---- layer 2 (12 MFMAs) ----
        HID(A2)
        PACKH(ca,cb,u0,u1);
        XCHG(xB);

        // ---- layer 3 (12 MFMAs) ----
        HID(A3)

        // ---- layer 4: own partials + cross-wave merge + phi reduce ----
        float z0p = 0.f, z1p = 0.f;
#pragma unroll
        for (int r = 0; r < 4; ++r){
            float hv = fmaxf(ca[r], 0.f);
            z0p = fmaf(hv, w4a[r],   z0p);
            z1p = fmaf(hv, w4b[r],   z1p);
        }
#pragma unroll
        for (int r = 0; r < 4; ++r){
            float hv = fmaxf(cb[r], 0.f);
            z0p = fmaf(hv, w4a[4+r], z0p);
            z1p = fmaf(hv, w4b[4+r], z1p);
        }
        float2v zp = {z0p, z1p};
        zxch[wid][lane] = zp;
        __syncthreads();
        float2v oz = zxch[wid^1][lane];
        z0p += oz[0]; z1p += oz[1];
        z0p += __shfl_xor(z0p, 16, 64);
        z1p += __shfl_xor(z1p, 16, 64);
        z0p += __shfl_xor(z0p, 32, 64);
        z1p += __shfl_xor(z1p, 32, 64);
        float zz0 = z0p + b40;
        float zz1 = z1p + b41;

        // u = 0.5*tanh(z) = 0.5 - 1/(exp(2z)+1)
        float u0v = 0.5f - __builtin_amdgcn_rcpf(__expf(2.0f*zz0) + 1.0f);
        float u1v = 0.5f - __builtin_amdgcn_rcpf(__expf(2.0f*zz1) + 1.0f);

        // ---- dynamics (verified path) ----
        float th = ss[5]*DT, t2 = th*th;
        float sw = th * fmaf(t2, fmaf(t2, 8.3333333333e-3f, -1.6666666667e-1f), 1.0f);
        float cw = fmaf(t2, fmaf(t2, fmaf(t2, -1.3888888889e-3f, 4.1666666667e-2f), -0.5f), 1.0f);
        float nx = fmaf(ss[4]*ss[2], DT, ss[0]);
        float ny = fmaf(ss[4]*ss[3], DT, ss[1]);
        float nc = ss[2]*cw - ss[3]*sw;
        float ns = fmaf(ss[3], cw, nc*sw);           // uses c_new
        float nv = fminf(fmaxf(fmaf(u0v, DT, ss[4]), -0.1f), 0.3f);
        float nw = fminf(fmaxf(fmaf(u1v, DT, ss[5]), -PI4), PI4);

        // ---- stores: wave 0, one lane per row (verified scheme) ----
        if (wid == 0 && phi == 0){
            float2v uv  = {u0v, u1v};
            *(float2v*)uout = uv;
            float2v s01 = {nx, ny}, s23 = {nc, ns}, s45 = {nv, nw};
            *(float2v*)(sout    ) = s01;
            *(float2v*)(sout + 2) = s23;
            *(float2v*)(sout + 4) = s45;
        }
        uout += (size_t)BATCH * 2;
        sout += (size_t)BATCH * 6;

#pragma unroll
        for (int i = 0; i < 6; ++i) ps[i] = ss[i];
        ss[0]=nx; ss[1]=ny; ss[2]=nc; ss[3]=ns; ss[4]=nv; ss[5]=nw;
    }
#undef SPLITH
#undef PACKH
#undef XCHG
#undef HID
}

extern "C" void kernel_launch(void* const* d_in, const int* in_sizes, int n_in,
                              void* d_out, int out_size, void* d_ws, size_t ws_size,
                              hipStream_t stream)
{
    const float* state  = (const float*)d_in[0];
    const float* pstate = (const float*)d_in[1];
    const float* target = (const float*)d_in[2];
    const float* W1 = (const float*)d_in[3];
    const float* b1 = (const float*)d_in[4];
    const float* W2 = (const float*)d_in[5];
    const float* b2 = (const float*)d_in[6];
    const float* W3 = (const float*)d_in[7];
    const float* b3 = (const float*)d_in[8];
    const float* W4 = (const float*)d_in[9];
    const float* b4 = (const float*)d_in[10];
    float* out = (float*)d_out;

    dim3 grid(BATCH/16), block(128);
    mbrl_mfma2<<<grid, block, 0, stream>>>(state, pstate, target,
                                           W1,b1,W2,b2,W3,b3,W4,b4, out);
}

// Round 13
// 251.386 us; speedup vs baseline: 1.3987x; 1.3987x over previous
//
#include <hip/hip_runtime.h>
#include <hip/hip_bf16.h>
#include <stdint.h>
#include <math.h>

#define SEQ_LEN 256
#define BATCH   16384

typedef _Float16 half8  __attribute__((ext_vector_type(8)));
typedef _Float16 half2t __attribute__((ext_vector_type(2)));
typedef __attribute__((ext_vector_type(4))) float    floatx4;
typedef __attribute__((ext_vector_type(4))) uint32_t uint4v;
typedef __attribute__((ext_vector_type(2))) float    float2v;

__device__ __forceinline__ uint32_t pkh(float a, float b){
    return __builtin_bit_cast(uint32_t, __builtin_amdgcn_cvt_pkrtz(a, b));
}
__device__ __forceinline__ float h16lo(uint32_t p){
    return (float)__builtin_bit_cast(half2t, p)[0];
}
__device__ __forceinline__ float h16hi(uint32_t p){
    return (float)__builtin_bit_cast(half2t, p)[1];
}
__device__ __forceinline__ uint32_t pkh_rne(float a, float b){
    // two v_cvt_f16_f32 (RNE) + one shift-or; RNE halves the h-quant error vs RTZ
    uint32_t ua = (uint32_t)__builtin_bit_cast(unsigned short, (_Float16)a);
    uint32_t ub = (uint32_t)__builtin_bit_cast(unsigned short, (_Float16)b);
    return ua | (ub << 16);
}
__device__ __forceinline__ half8 ashfrag(uint4v u){ return __builtin_bit_cast(half8, u); }
#define MFMA_H(A,B,C) __builtin_amdgcn_mfma_f32_16x16x32_f16((A),(B),(C),0,0,0)

// r11 structure (1 wave / 16 rows, verified k-map kk=16(v>>1)+4phi+2(v&1)+q,
// C/D row=4phi+reg, shfl z-reduce, phi==0 store scheme), with the h-side
// residual dropped: h is a SINGLE RNE f16, W stays double-split (static).
// Hidden-layer terms: z = w0*h + w1*h + (b0+b1)*h[50] -> dropped Sum w*h1
// ~ 3.6e-4 z-error (bf16-anchor scaling: ~0.85/16 ~ 0.05 final absmax).
// MFMA 40/step (was 56), MKH per-pair 8->5 VALU ops, chain depth 6->4.
__global__ __launch_bounds__(64, 1) void mbrl_mfma(
    const float* __restrict__ state0, const float* __restrict__ pstate0,
    const float* __restrict__ target,
    const float* __restrict__ W1, const float* __restrict__ b1,
    const float* __restrict__ W2, const float* __restrict__ b2,
    const float* __restrict__ W3, const float* __restrict__ b3,
    const float* __restrict__ W4, const float* __restrict__ b4,
    float* __restrict__ out)
{
    const int lane = threadIdx.x & 63;
    const int c16  = lane & 15;
    const int phi  = lane >> 4;
    const int rowg = (int)blockIdx.x * 16 + c16;

    // ---------------- Layer-1 A tiles: P = w0|b0|w0, Q = w1|b1|w1 ----------------
    half8 P1[4], Q1[4];
#pragma unroll
    for (int t = 0; t < 4; ++t){
        const int j = 16*t + c16;
        uint4v uP, uQ;
#pragma unroll
        for (int v = 0; v < 4; ++v){
            float pP[2], pQ[2];
#pragma unroll
            for (int q = 0; q < 2; ++q){
                const int kk = 16*(v>>1) + 4*phi + 2*(v&1) + q;
                float w = 0.f;
                if (j < 50){
                    if (kk < 12)                  w = W1[kk*50 + j];
                    else if (kk == 12)            w = b1[j];
                    else if (kk >= 16 && kk < 28) w = W1[(kk-16)*50 + j];
                }
                float s0 = (float)(_Float16)w;
                pP[q] = s0; pQ[q] = w - s0;
            }
            uP[v] = pkh(pP[0], pP[1]);
            uQ[v] = pkh(pQ[0], pQ[1]);
        }
        P1[t] = ashfrag(uP); Q1[t] = ashfrag(uQ);
    }

    // ---------------- Layer-2/3 A tiles: splits s=0 (w0,b0), s=1 (w1,b1) ----------------
    half8 A2[2][4][2], A3[2][4][2];
#pragma unroll
    for (int t = 0; t < 4; ++t){
        const int j = 16*t + c16;
#pragma unroll
        for (int kt = 0; kt < 2; ++kt){
            uint4v u2[2], u3[2];
#pragma unroll
            for (int v = 0; v < 4; ++v){
                float p2[2][2], p3[2][2];
#pragma unroll
                for (int q = 0; q < 2; ++q){
                    const int kk = 32*kt + 16*(v>>1) + 4*phi + 2*(v&1) + q;
                    float w2v = 0.f, w3v = 0.f;
                    if (j < 50){
                        if (kk < 50){ w2v = W2[kk*50 + j]; w3v = W3[kk*50 + j]; }
                        else if (kk == 50){ w2v = b2[j]; w3v = b3[j]; }
                    }
                    float a0  = (float)(_Float16)w2v;
                    float c0s = (float)(_Float16)w3v;
                    p2[0][q] = a0;  p2[1][q] = w2v - a0;
                    p3[0][q] = c0s; p3[1][q] = w3v - c0s;
                }
#pragma unroll
                for (int s = 0; s < 2; ++s){
                    u2[s][v] = pkh(p2[s][0], p2[s][1]);
                    u3[s][v] = pkh(p3[s][0], p3[s][1]);
                }
            }
#pragma unroll
            for (int s = 0; s < 2; ++s){
                A2[s][t][kt] = ashfrag(u2[s]); A3[s][t][kt] = ashfrag(u3[s]);
            }
        }
    }

    // ---------------- Layer-4 per-lane f32 weights (r9-verified) ----------------
    float w4a[16], w4b[16];
#pragma unroll
    for (int t = 0; t < 4; ++t)
#pragma unroll
        for (int r = 0; r < 4; ++r){
            const int j = 16*t + 4*phi + r;
            w4a[4*t+r] = (j < 50) ? W4[j*2 + 0] : 0.f;
            w4b[4*t+r] = (j < 50) ? W4[j*2 + 1] : 0.f;
        }
    const float b40 = b4[0], b41 = b4[1];

    // ---------------- per-row state (duplicated across phi groups) ----------------
    float ps[6], ss[6], tg[6];
#pragma unroll
    for (int i = 0; i < 6; ++i){
        ps[i] = pstate0[(size_t)rowg*6 + i];
        ss[i] = state0 [(size_t)rowg*6 + i];
        tg[i] = target [(size_t)rowg*6 + i];
    }

    const float DT  = 0.05f;
    const float PI4 = 0.78539816339744830962f;
    const floatx4 z4 = {0.f,0.f,0.f,0.f};
    const uint32_t ONE_H = 0x00003C00u;    // (f16 1.0, f16 0.0)

    float* uout = out + (size_t)rowg * 2;
    float* sout = out + (size_t)SEQ_LEN * BATCH * 2 + (size_t)rowg * 6;

    half8 H0a, H0b;

    // X double-split (RTZ pack + residual) — only 2 per step, keep r11 form
#define SPLITH(HA,HB,PK0,PK1) do{                                      \
        PK0 = pkh((HA),(HB));                                          \
        float _a = h16lo(PK0), _b = h16hi(PK0);                        \
        PK1 = pkh((HA)-_a, (HB)-_b);                                   \
    }while(0)

    // h -> single RNE f16 pack (5 ops/pair: 2 fmax + 2 cvt + 1 shl-or)
#define MKH(cc0,cc1,cc2,cc3) do{                                                   \
        uint4v u0a, u0b;                                                           \
        u0a[0] = pkh_rne(fmaxf(cc0[0],0.f), fmaxf(cc0[1],0.f));                    \
        u0a[1] = pkh_rne(fmaxf(cc0[2],0.f), fmaxf(cc0[3],0.f));                    \
        u0a[2] = pkh_rne(fmaxf(cc1[0],0.f), fmaxf(cc1[1],0.f));                    \
        u0a[3] = pkh_rne(fmaxf(cc1[2],0.f), fmaxf(cc1[3],0.f));                    \
        u0b[0] = pkh_rne(fmaxf(cc2[0],0.f), fmaxf(cc2[1],0.f));                    \
        u0b[1] = pkh_rne(fmaxf(cc2[2],0.f), fmaxf(cc2[3],0.f));                    \
        u0b[2] = pkh_rne(fmaxf(cc3[0],0.f), fmaxf(cc3[1],0.f));                    \
        u0b[3] = pkh_rne(fmaxf(cc3[2],0.f), fmaxf(cc3[3],0.f));                    \
        if (phi == 0) u0b[3] = ONE_H;     /* h[50]=1, h[51]=0 */                   \
        H0a = ashfrag(u0a); H0b = ashfrag(u0b);                                    \
    }while(0)

    // hidden layer: 2 terms (w0*h, w1*h), round-robin, 16 MFMAs, 4-deep chains
#define HID_RR(A)                                                                            \
        c0=MFMA_H(A[0][0][0],H0a,z4); c1=MFMA_H(A[0][1][0],H0a,z4); c2=MFMA_H(A[0][2][0],H0a,z4); c3=MFMA_H(A[0][3][0],H0a,z4); \
        c0=MFMA_H(A[0][0][1],H0b,c0); c1=MFMA_H(A[0][1][1],H0b,c1); c2=MFMA_H(A[0][2][1],H0b,c2); c3=MFMA_H(A[0][3][1],H0b,c3); \
        c0=MFMA_H(A[1][0][0],H0a,c0); c1=MFMA_H(A[1][1][0],H0a,c1); c2=MFMA_H(A[1][2][0],H0a,c2); c3=MFMA_H(A[1][3][0],H0a,c3); \
        c0=MFMA_H(A[1][0][1],H0b,c0); c1=MFMA_H(A[1][1][1],H0b,c1); c2=MFMA_H(A[1][2][1],H0b,c2); c3=MFMA_H(A[1][3][1],H0b,c3);

#define L4ACC(CT,T) do{                                                   \
        _Pragma("unroll")                                                 \
        for (int r = 0; r < 4; ++r){                                      \
            float hv = fmaxf(CT[r], 0.f);                                 \
            z0p = fmaf(hv, w4a[4*(T)+r], z0p);                            \
            z1p = fmaf(hv, w4b[4*(T)+r], z1p);                            \
        }                                                                 \
    }while(0)

    for (int t = 0; t < SEQ_LEN; ++t){
        // ---- X build: f16 double-split (r11-verified) ----
        float X0=ps[0]-tg[0], X1=ps[1]-tg[1], X2=ps[2]-tg[2];
        float X3=ps[3]-tg[3], X4=ps[4]-tg[4], X5=ps[5]-tg[5];
        float X6=ss[0]-tg[0], X7=ss[1]-tg[1], X8=ss[2]-tg[2];
        float X9=ss[3]-tg[3], X10=ss[4]-tg[4], X11=ss[5]-tg[5];
        float xs0 = (phi==0)?X0:(phi==1)?X4:(phi==2)?X8 :0.f;
        float xs1 = (phi==0)?X1:(phi==1)?X5:(phi==2)?X9 :0.f;
        float xs2 = (phi==0)?X2:(phi==1)?X6:(phi==2)?X10:0.f;
        float xs3 = (phi==0)?X3:(phi==1)?X7:(phi==2)?X11:0.f;
        uint32_t pH01,pL01,pH23,pL23;
        SPLITH(xs0,xs1,pH01,pL01);
        SPLITH(xs2,xs3,pH23,pL23);
        uint4v f1;
        f1[0] = (phi==3) ? ONE_H : pH01;   // k12 = 1.0 on phi==3
        f1[1] = pH23;
        f1[2] = pL01;
        f1[3] = pL23;
        const half8 F1 = ashfrag(f1);

        // ---- layer 1 (8 MFMAs, r11-verified) ----
        floatx4 c0, c1, c2, c3;
        c0=MFMA_H(P1[0],F1,z4); c1=MFMA_H(P1[1],F1,z4); c2=MFMA_H(P1[2],F1,z4); c3=MFMA_H(P1[3],F1,z4);
        c0=MFMA_H(Q1[0],F1,c0); c1=MFMA_H(Q1[1],F1,c1); c2=MFMA_H(Q1[2],F1,c2); c3=MFMA_H(Q1[3],F1,c3);
        MKH(c0,c1,c2,c3);

        // ---- layer 2 (16 MFMAs) ----
        HID_RR(A2)
        MKH(c0,c1,c2,c3);

        // ---- layer 3 (16 MFMAs) ----
        HID_RR(A3)

        // ---- layer 4: per-lane f32 partials + phi reduce (r9-verified) ----
        float z0p = 0.f, z1p = 0.f;
        L4ACC(c0,0); L4ACC(c1,1); L4ACC(c2,2); L4ACC(c3,3);
        z0p += __shfl_xor(z0p, 16, 64);
        z1p += __shfl_xor(z1p, 16, 64);
        z0p += __shfl_xor(z0p, 32, 64);
        z1p += __shfl_xor(z1p, 32, 64);
        float zz0 = z0p + b40;
        float zz1 = z1p + b41;

        // u = 0.5*tanh(z) = 0.5 - 1/(exp(2z)+1)
        float u0 = 0.5f - __builtin_amdgcn_rcpf(__expf(2.0f*zz0) + 1.0f);
        float u1 = 0.5f - __builtin_amdgcn_rcpf(__expf(2.0f*zz1) + 1.0f);

        // ---- dynamics: poly sin/cos (verified path) ----
        float th = ss[5]*DT, t2 = th*th;
        float sw = th * fmaf(t2, fmaf(t2, 8.3333333333e-3f, -1.6666666667e-1f), 1.0f);
        float cw = fmaf(t2, fmaf(t2, fmaf(t2, -1.3888888889e-3f, 4.1666666667e-2f), -0.5f), 1.0f);
        float nx = fmaf(ss[4]*ss[2], DT, ss[0]);
        float ny = fmaf(ss[4]*ss[3], DT, ss[1]);
        float nc = ss[2]*cw - ss[3]*sw;
        float ns = fmaf(ss[3], cw, nc*sw);           // uses c_new
        float nv = fminf(fmaxf(fmaf(u0, DT, ss[4]), -0.1f), 0.3f);
        float nw = fminf(fmaxf(fmaf(u1, DT, ss[5]), -PI4), PI4);

        // ---- verified store scheme: one lane per row writes everything ----
        if (phi == 0){
            float2v uv  = {u0, u1};
            *(float2v*)uout = uv;
            float2v s01 = {nx, ny}, s23 = {nc, ns}, s45 = {nv, nw};
            *(float2v*)(sout    ) = s01;
            *(float2v*)(sout + 2) = s23;
            *(float2v*)(sout + 4) = s45;
        }
        uout += (size_t)BATCH * 2;
        sout += (size_t)BATCH * 6;

#pragma unroll
        for (int i = 0; i < 6; ++i) ps[i] = ss[i];
        ss[0]=nx; ss[1]=ny; ss[2]=nc; ss[3]=ns; ss[4]=nv; ss[5]=nw;
    }
#undef MKH
#undef SPLITH
#undef HID_RR
#undef L4ACC
}

extern "C" void kernel_launch(void* const* d_in, const int* in_sizes, int n_in,
                              void* d_out, int out_size, void* d_ws, size_t ws_size,
                              hipStream_t stream)
{
    const float* state  = (const float*)d_in[0];
    const float* pstate = (const float*)d_in[1];
    const float* target = (const float*)d_in[2];
    const float* W1 = (const float*)d_in[3];
    const float* b1 = (const float*)d_in[4];
    const float* W2 = (const float*)d_in[5];
    const float* b2 = (const float*)d_in[6];
    const float* W3 = (const float*)d_in[7];
    const float* b3 = (const float*)d_in[8];
    const float* W4 = (const float*)d_in[9];
    const float* b4 = (const float*)d_in[10];
    float* out = (float*)d_out;

    dim3 grid(BATCH/16), block(64);
    mbrl_mfma<<<grid, block, 0, stream>>>(state, pstate, target,
                                          W1,b1,W2,b2,W3,b3,W4,b4, out);
}

// Round 15
// 237.255 us; speedup vs baseline: 1.4820x; 1.0596x over previous
//
#include <hip/hip_runtime.h>
#include <hip/hip_bf16.h>
#include <stdint.h>
#include <math.h>

#define SEQ_LEN 256
#define BATCH   16384

typedef _Float16 half8  __attribute__((ext_vector_type(8)));
typedef _Float16 half2t __attribute__((ext_vector_type(2)));
typedef __attribute__((ext_vector_type(4))) float    floatx4;
typedef __attribute__((ext_vector_type(4))) uint32_t uint4v;
typedef __attribute__((ext_vector_type(2))) float    float2v;

__device__ __forceinline__ uint32_t pkh(float a, float b){
    return __builtin_bit_cast(uint32_t, __builtin_amdgcn_cvt_pkrtz(a, b));
}
__device__ __forceinline__ float h16lo(uint32_t p){
    return (float)__builtin_bit_cast(half2t, p)[0];
}
__device__ __forceinline__ float h16hi(uint32_t p){
    return (float)__builtin_bit_cast(half2t, p)[1];
}
__device__ __forceinline__ uint32_t pkh_rne(float a, float b){
    uint32_t ua = (uint32_t)__builtin_bit_cast(unsigned short, (_Float16)a);
    uint32_t ub = (uint32_t)__builtin_bit_cast(unsigned short, (_Float16)b);
    return ua | (ub << 16);
}
__device__ __forceinline__ half8 ashfrag(uint4v u){ return __builtin_bit_cast(half8, u); }
#define MFMA_H(A,B,C) __builtin_amdgcn_mfma_f32_16x16x32_f16((A),(B),(C),0,0,0)

// r13-exact numerics (W double-split f16, h single RNE f16, X double-split)
// + r14's numerically-identical X-build (per-lane source regs). Error ledger
// (measured): W-residual drop = +0.14 (systematic, FATAL r14); h-residual
// drop = +0.016 (random, r13); floor 0.0156 (r11). => W stays double.
// MFMA 40/step. All k-map / C-D / repack / store formulas HW-verified r5-r13.
__global__ __launch_bounds__(64, 1) void mbrl_mfma(
    const float* __restrict__ state0, const float* __restrict__ pstate0,
    const float* __restrict__ target,
    const float* __restrict__ W1, const float* __restrict__ b1,
    const float* __restrict__ W2, const float* __restrict__ b2,
    const float* __restrict__ W3, const float* __restrict__ b3,
    const float* __restrict__ W4, const float* __restrict__ b4,
    float* __restrict__ out)
{
    const int lane = threadIdx.x & 63;
    const int c16  = lane & 15;
    const int phi  = lane >> 4;
    const int rowg = (int)blockIdx.x * 16 + c16;

    // ---------------- Layer-1 A tiles: P = w0|b0|w0, Q = w1|b1|w1 ----------------
    half8 P1[4], Q1[4];
#pragma unroll
    for (int t = 0; t < 4; ++t){
        const int j = 16*t + c16;
        uint4v uP, uQ;
#pragma unroll
        for (int v = 0; v < 4; ++v){
            float pP[2], pQ[2];
#pragma unroll
            for (int q = 0; q < 2; ++q){
                const int kk = 16*(v>>1) + 4*phi + 2*(v&1) + q;
                float w = 0.f;
                if (j < 50){
                    if (kk < 12)                  w = W1[kk*50 + j];
                    else if (kk == 12)            w = b1[j];
                    else if (kk >= 16 && kk < 28) w = W1[(kk-16)*50 + j];
                }
                float s0 = (float)(_Float16)w;
                pP[q] = s0; pQ[q] = w - s0;
            }
            uP[v] = pkh(pP[0], pP[1]);
            uQ[v] = pkh(pQ[0], pQ[1]);
        }
        P1[t] = ashfrag(uP); Q1[t] = ashfrag(uQ);
    }

    // ---------------- Layer-2/3 A tiles: splits s=0 (w0,b0), s=1 (w1,b1) ----------------
    half8 A2[2][4][2], A3[2][4][2];
#pragma unroll
    for (int t = 0; t < 4; ++t){
        const int j = 16*t + c16;
#pragma unroll
        for (int kt = 0; kt < 2; ++kt){
            uint4v u2[2], u3[2];
#pragma unroll
            for (int v = 0; v < 4; ++v){
                float p2[2][2], p3[2][2];
#pragma unroll
                for (int q = 0; q < 2; ++q){
                    const int kk = 32*kt + 16*(v>>1) + 4*phi + 2*(v&1) + q;
                    float w2v = 0.f, w3v = 0.f;
                    if (j < 50){
                        if (kk < 50){ w2v = W2[kk*50 + j]; w3v = W3[kk*50 + j]; }
                        else if (kk == 50){ w2v = b2[j]; w3v = b3[j]; }
                    }
                    float a0  = (float)(_Float16)w2v;
                    float c0s = (float)(_Float16)w3v;
                    p2[0][q] = a0;  p2[1][q] = w2v - a0;
                    p3[0][q] = c0s; p3[1][q] = w3v - c0s;
                }
#pragma unroll
                for (int s = 0; s < 2; ++s){
                    u2[s][v] = pkh(p2[s][0], p2[s][1]);
                    u3[s][v] = pkh(p3[s][0], p3[s][1]);
                }
            }
#pragma unroll
            for (int s = 0; s < 2; ++s){
                A2[s][t][kt] = ashfrag(u2[s]); A3[s][t][kt] = ashfrag(u3[s]);
            }
        }
    }

    // ---------------- Layer-4 per-lane f32 weights (r9-verified) ----------------
    float w4a[16], w4b[16];
#pragma unroll
    for (int t = 0; t < 4; ++t)
#pragma unroll
        for (int r = 0; r < 4; ++r){
            const int j = 16*t + 4*phi + r;
            w4a[4*t+r] = (j < 50) ? W4[j*2 + 0] : 0.f;
            w4b[4*t+r] = (j < 50) ? W4[j*2 + 1] : 0.f;
        }
    const float b40 = b4[0], b41 = b4[1];

    // ---------------- per-row state + per-lane X sources (r14, bit-identical) ----------------
    float ss[6];
#pragma unroll
    for (int i = 0; i < 6; ++i) ss[i] = state0[(size_t)rowg*6 + i];

    float tgs0, tgs1, tgs2, tgs3;
    {
        const float* tg = target + (size_t)rowg*6;
        tgs0 = (phi==0) ? tg[0] : (phi==1) ? tg[4] : (phi==2) ? tg[2] : 0.f;
        tgs1 = (phi==0) ? tg[1] : (phi==1) ? tg[5] : (phi==2) ? tg[3] : 0.f;
        tgs2 = (phi==0) ? tg[2] : (phi==1) ? tg[0] : (phi==2) ? tg[4] : 0.f;
        tgs3 = (phi==0) ? tg[3] : (phi==1) ? tg[1] : (phi==2) ? tg[5] : 0.f;
    }
    float a0, a1, a2, a3;
    {
        const float* ps0 = pstate0 + (size_t)rowg*6;
        a0 = (phi==0) ? ps0[0] : (phi==1) ? ps0[4] : (phi==2) ? ss[2] : 0.f;
        a1 = (phi==0) ? ps0[1] : (phi==1) ? ps0[5] : (phi==2) ? ss[3] : 0.f;
        a2 = (phi==0) ? ps0[2] : (phi==1) ? ss[0]  : (phi==2) ? ss[4] : 0.f;
        a3 = (phi==0) ? ps0[3] : (phi==1) ? ss[1]  : (phi==2) ? ss[5] : 0.f;
    }

    const float DT  = 0.05f;
    const float PI4 = 0.78539816339744830962f;
    const floatx4 z4 = {0.f,0.f,0.f,0.f};
    const uint32_t ONE_H = 0x00003C00u;    // (f16 1.0, f16 0.0)

    float* uout = out + (size_t)rowg * 2;
    float* sout = out + (size_t)SEQ_LEN * BATCH * 2 + (size_t)rowg * 6;

    half8 H0a, H0b;

#define SPLITH(HA,HB,PK0,PK1) do{                                      \
        PK0 = pkh((HA),(HB));                                          \
        float _a = h16lo(PK0), _b = h16hi(PK0);                        \
        PK1 = pkh((HA)-_a, (HB)-_b);                                   \
    }while(0)

    // h -> single RNE f16 pack (r13-verified)
#define MKH(cc0,cc1,cc2,cc3) do{                                                   \
        uint4v u0a, u0b;                                                           \
        u0a[0] = pkh_rne(fmaxf(cc0[0],0.f), fmaxf(cc0[1],0.f));                    \
        u0a[1] = pkh_rne(fmaxf(cc0[2],0.f), fmaxf(cc0[3],0.f));                    \
        u0a[2] = pkh_rne(fmaxf(cc1[0],0.f), fmaxf(cc1[1],0.f));                    \
        u0a[3] = pkh_rne(fmaxf(cc1[2],0.f), fmaxf(cc1[3],0.f));                    \
        u0b[0] = pkh_rne(fmaxf(cc2[0],0.f), fmaxf(cc2[1],0.f));                    \
        u0b[1] = pkh_rne(fmaxf(cc2[2],0.f), fmaxf(cc2[3],0.f));                    \
        u0b[2] = pkh_rne(fmaxf(cc3[0],0.f), fmaxf(cc3[1],0.f));                    \
        u0b[3] = pkh_rne(fmaxf(cc3[2],0.f), fmaxf(cc3[3],0.f));                    \
        if (phi == 0) u0b[3] = ONE_H;     /* h[50]=1, h[51]=0 */                   \
        H0a = ashfrag(u0a); H0b = ashfrag(u0b);                                    \
    }while(0)

    // hidden layer: 2 terms (w0*h, w1*h), round-robin, 16 MFMAs (r13-verified)
#define HID_RR(A)                                                                            \
        c0=MFMA_H(A[0][0][0],H0a,z4); c1=MFMA_H(A[0][1][0],H0a,z4); c2=MFMA_H(A[0][2][0],H0a,z4); c3=MFMA_H(A[0][3][0],H0a,z4); \
        c0=MFMA_H(A[0][0][1],H0b,c0); c1=MFMA_H(A[0][1][1],H0b,c1); c2=MFMA_H(A[0][2][1],H0b,c2); c3=MFMA_H(A[0][3][1],H0b,c3); \
        c0=MFMA_H(A[1][0][0],H0a,c0); c1=MFMA_H(A[1][1][0],H0a,c1); c2=MFMA_H(A[1][2][0],H0a,c2); c3=MFMA_H(A[1][3][0],H0a,c3); \
        c0=MFMA_H(A[1][0][1],H0b,c0); c1=MFMA_H(A[1][1][1],H0b,c1); c2=MFMA_H(A[1][2][1],H0b,c2); c3=MFMA_H(A[1][3][1],H0b,c3);

#define L4ACC(CT,T) do{                                                   \
        _Pragma("unroll")                                                 \
        for (int r = 0; r < 4; ++r){                                      \
            float hv = fmaxf(CT[r], 0.f);                                 \
            z0p = fmaf(hv, w4a[4*(T)+r], z0p);                            \
            z1p = fmaf(hv, w4b[4*(T)+r], z1p);                            \
        }                                                                 \
    }while(0)

    for (int t = 0; t < SEQ_LEN; ++t){
        // ---- X build from per-lane sources (f16 double-split, r11/r13-verified values) ----
        float xs0 = a0 - tgs0, xs1 = a1 - tgs1;
        float xs2 = a2 - tgs2, xs3 = a3 - tgs3;
        uint32_t pH01,pL01,pH23,pL23;
        SPLITH(xs0,xs1,pH01,pL01);
        SPLITH(xs2,xs3,pH23,pL23);
        uint4v f1;
        f1[0] = (phi==3) ? ONE_H : pH01;   // k12 = 1.0 on phi==3; rest 0 naturally
        f1[1] = pH23;
        f1[2] = pL01;
        f1[3] = pL23;
        const half8 F1 = ashfrag(f1);

        // ---- layer 1 (8 MFMAs: P then Q, round-robin) ----
        floatx4 c0, c1, c2, c3;
        c0=MFMA_H(P1[0],F1,z4); c1=MFMA_H(P1[1],F1,z4); c2=MFMA_H(P1[2],F1,z4); c3=MFMA_H(P1[3],F1,z4);
        c0=MFMA_H(Q1[0],F1,c0); c1=MFMA_H(Q1[1],F1,c1); c2=MFMA_H(Q1[2],F1,c2); c3=MFMA_H(Q1[3],F1,c3);
        MKH(c0,c1,c2,c3);

        // ---- layer 2 (16 MFMAs) ----
        HID_RR(A2)
        MKH(c0,c1,c2,c3);

        // ---- layer 3 (16 MFMAs) ----
        HID_RR(A3)

        // ---- layer 4: per-lane f32 partials + phi reduce (r9-verified) ----
        float z0p = 0.f, z1p = 0.f;
        L4ACC(c0,0); L4ACC(c1,1); L4ACC(c2,2); L4ACC(c3,3);
        z0p += __shfl_xor(z0p, 16, 64);
        z1p += __shfl_xor(z1p, 16, 64);
        z0p += __shfl_xor(z0p, 32, 64);
        z1p += __shfl_xor(z1p, 32, 64);
        float zz0 = z0p + b40;
        float zz1 = z1p + b41;

        // u = 0.5*tanh(z) = 0.5 - 1/(exp(2z)+1)
        float u0 = 0.5f - __builtin_amdgcn_rcpf(__expf(2.0f*zz0) + 1.0f);
        float u1 = 0.5f - __builtin_amdgcn_rcpf(__expf(2.0f*zz1) + 1.0f);

        // ---- dynamics: poly sin/cos (verified path) ----
        float th = ss[5]*DT, t2 = th*th;
        float sw = th * fmaf(t2, fmaf(t2, 8.3333333333e-3f, -1.6666666667e-1f), 1.0f);
        float cw = fmaf(t2, fmaf(t2, fmaf(t2, -1.3888888889e-3f, 4.1666666667e-2f), -0.5f), 1.0f);
        float nx = fmaf(ss[4]*ss[2], DT, ss[0]);
        float ny = fmaf(ss[4]*ss[3], DT, ss[1]);
        float nc = ss[2]*cw - ss[3]*sw;
        float ns = fmaf(ss[3], cw, nc*sw);           // uses c_new
        float nv = fminf(fmaxf(fmaf(u0, DT, ss[4]), -0.1f), 0.3f);
        float nw = fminf(fmaxf(fmaf(u1, DT, ss[5]), -PI4), PI4);

        // ---- verified store scheme: one lane per row writes everything ----
        if (phi == 0){
            float2v uv  = {u0, u1};
            *(float2v*)uout = uv;
            float2v s01 = {nx, ny}, s23 = {nc, ns}, s45 = {nv, nw};
            *(float2v*)(sout    ) = s01;
            *(float2v*)(sout + 2) = s23;
            *(float2v*)(sout + 4) = s45;
        }
        uout += (size_t)BATCH * 2;
        sout += (size_t)BATCH * 6;

        // ---- update per-lane X sources (next ps = old ss; next ss = new) ----
        a0 = (phi==0) ? ss[0] : (phi==1) ? ss[4] : (phi==2) ? nc : a0;
        a1 = (phi==0) ? ss[1] : (phi==1) ? ss[5] : (phi==2) ? ns : a1;
        a2 = (phi==0) ? ss[2] : (phi==1) ? nx    : (phi==2) ? nv : a2;
        a3 = (phi==0) ? ss[3] : (phi==1) ? ny    : (phi==2) ? nw : a3;

        ss[0]=nx; ss[1]=ny; ss[2]=nc; ss[3]=ns; ss[4]=nv; ss[5]=nw;
    }
#undef MKH
#undef SPLITH
#undef HID_RR
#undef L4ACC
}

extern "C" void kernel_launch(void* const* d_in, const int* in_sizes, int n_in,
                              void* d_out, int out_size, void* d_ws, size_t ws_size,
                              hipStream_t stream)
{
    const float* state  = (const float*)d_in[0];
    const float* pstate = (const float*)d_in[1];
    const float* target = (const float*)d_in[2];
    const float* W1 = (const float*)d_in[3];
    const float* b1 = (const float*)d_in[4];
    const float* W2 = (const float*)d_in[5];
    const float* b2 = (const float*)d_in[6];
    const float* W3 = (const float*)d_in[7];
    const float* b3 = (const float*)d_in[8];
    const float* W4 = (const float*)d_in[9];
    const float* b4 = (const float*)d_in[10];
    float* out = (float*)d_out;

    dim3 grid(BATCH/16), block(64);
    mbrl_mfma<<<grid, block, 0, stream>>>(state, pstate, target,
                                          W1,b1,W2,b2,W3,b3,W4,b4, out);
}

// Round 16
// 236.082 us; speedup vs baseline: 1.4893x; 1.0050x over previous
//
#include <hip/hip_runtime.h>
#include <hip/hip_bf16.h>
#include <stdint.h>
#include <math.h>

#define SEQ_LEN 256
#define BATCH   16384

typedef _Float16 half8  __attribute__((ext_vector_type(8)));
typedef _Float16 half2t __attribute__((ext_vector_type(2)));
typedef __attribute__((ext_vector_type(4))) float    floatx4;
typedef __attribute__((ext_vector_type(4))) uint32_t uint4v;
typedef __attribute__((ext_vector_type(2))) float    float2v;

__device__ __forceinline__ uint32_t pkh(float a, float b){
    return __builtin_bit_cast(uint32_t, __builtin_amdgcn_cvt_pkrtz(a, b));
}
__device__ __forceinline__ float h16lo(uint32_t p){
    return (float)__builtin_bit_cast(half2t, p)[0];
}
__device__ __forceinline__ float h16hi(uint32_t p){
    return (float)__builtin_bit_cast(half2t, p)[1];
}
__device__ __forceinline__ uint32_t pkh_rne(float a, float b){
    uint32_t ua = (uint32_t)__builtin_bit_cast(unsigned short, (_Float16)a);
    uint32_t ub = (uint32_t)__builtin_bit_cast(unsigned short, (_Float16)b);
    return ua | (ub << 16);
}
__device__ __forceinline__ half8 ashfrag(uint4v u){ return __builtin_bit_cast(half8, u); }
#define MFMA_H(A,B,C) __builtin_amdgcn_mfma_f32_16x16x32_f16((A),(B),(C),0,0,0)

// VALU-pipe lane reductions (bit-identical to z+shfl_xor versions)
__device__ __forceinline__ float xor16_sum(float z){
#if __has_builtin(__builtin_amdgcn_permlane16_swap)
    uint32_t u = __builtin_bit_cast(uint32_t, z);
    auto p = __builtin_amdgcn_permlane16_swap(u, u, false, false);
    return __builtin_bit_cast(float, (uint32_t)p[0]) + __builtin_bit_cast(float, (uint32_t)p[1]);
#else
    return z + __shfl_xor(z, 16, 64);
#endif
}
__device__ __forceinline__ float xor32_sum(float z){
#if __has_builtin(__builtin_amdgcn_permlane32_swap)
    uint32_t u = __builtin_bit_cast(uint32_t, z);
    auto p = __builtin_amdgcn_permlane32_swap(u, u, false, false);
    return __builtin_bit_cast(float, (uint32_t)p[0]) + __builtin_bit_cast(float, (uint32_t)p[1]);
#else
    return z + __shfl_xor(z, 32, 64);
#endif
}

// r15 numerics (W double-split f16, h single RNE f16, X double-split) with the
// u->X->L1 serial chain broken: F1(t+1) is built with the two u-dependent
// slots (k=10,11 and lo-twins 26,27) zeroed and the 8 L1 MFMAs are issued
// BEFORE the L4 reduce/tanh tail (MFMA pipe overlaps the VALU tail); after u
// arrives, an exact f32 rank-2 correction c += W1[10,j]*(nv-tg4)+W1[11,j]*(nw-tg5)
// restores those slots (more accurate than the f16 path it replaces).
// Reduce uses permlane16/32_swap (VALU) instead of DS shfl - bit-identical.
__global__ __launch_bounds__(64, 1) void mbrl_mfma(
    const float* __restrict__ state0, const float* __restrict__ pstate0,
    const float* __restrict__ target,
    const float* __restrict__ W1, const float* __restrict__ b1,
    const float* __restrict__ W2, const float* __restrict__ b2,
    const float* __restrict__ W3, const float* __restrict__ b3,
    const float* __restrict__ W4, const float* __restrict__ b4,
    float* __restrict__ out)
{
    const int lane = threadIdx.x & 63;
    const int c16  = lane & 15;
    const int phi  = lane >> 4;
    const int rowg = (int)blockIdx.x * 16 + c16;

    // ---------------- Layer-1 A tiles: P = w0|b0|w0, Q = w1|b1|w1 (r15) ----------------
    half8 P1[4], Q1[4];
#pragma unroll
    for (int t = 0; t < 4; ++t){
        const int j = 16*t + c16;
        uint4v uP, uQ;
#pragma unroll
        for (int v = 0; v < 4; ++v){
            float pP[2], pQ[2];
#pragma unroll
            for (int q = 0; q < 2; ++q){
                const int kk = 16*(v>>1) + 4*phi + 2*(v&1) + q;
                float w = 0.f;
                if (j < 50){
                    if (kk < 12)                  w = W1[kk*50 + j];
                    else if (kk == 12)            w = b1[j];
                    else if (kk >= 16 && kk < 28) w = W1[(kk-16)*50 + j];
                }
                float s0 = (float)(_Float16)w;
                pP[q] = s0; pQ[q] = w - s0;
            }
            uP[v] = pkh(pP[0], pP[1]);
            uQ[v] = pkh(pQ[0], pQ[1]);
        }
        P1[t] = ashfrag(uP); Q1[t] = ashfrag(uQ);
    }

    // ---------------- Layer-2/3 A tiles: double-split (r15) ----------------
    half8 A2[2][4][2], A3[2][4][2];
#pragma unroll
    for (int t = 0; t < 4; ++t){
        const int j = 16*t + c16;
#pragma unroll
        for (int kt = 0; kt < 2; ++kt){
            uint4v u2[2], u3[2];
#pragma unroll
            for (int v = 0; v < 4; ++v){
                float p2[2][2], p3[2][2];
#pragma unroll
                for (int q = 0; q < 2; ++q){
                    const int kk = 32*kt + 16*(v>>1) + 4*phi + 2*(v&1) + q;
                    float w2v = 0.f, w3v = 0.f;
                    if (j < 50){
                        if (kk < 50){ w2v = W2[kk*50 + j]; w3v = W3[kk*50 + j]; }
                        else if (kk == 50){ w2v = b2[j]; w3v = b3[j]; }
                    }
                    float a0  = (float)(_Float16)w2v;
                    float c0s = (float)(_Float16)w3v;
                    p2[0][q] = a0;  p2[1][q] = w2v - a0;
                    p3[0][q] = c0s; p3[1][q] = w3v - c0s;
                }
#pragma unroll
                for (int s = 0; s < 2; ++s){
                    u2[s][v] = pkh(p2[s][0], p2[s][1]);
                    u3[s][v] = pkh(p3[s][0], p3[s][1]);
                }
            }
#pragma unroll
            for (int s = 0; s < 2; ++s){
                A2[s][t][kt] = ashfrag(u2[s]); A3[s][t][kt] = ashfrag(u3[s]);
            }
        }
    }

    // ---------------- Layer-4 per-lane f32 weights (r9-verified) ----------------
    float w4a[16], w4b[16];
#pragma unroll
    for (int t = 0; t < 4; ++t)
#pragma unroll
        for (int r = 0; r < 4; ++r){
            const int j = 16*t + 4*phi + r;
            w4a[4*t+r] = (j < 50) ? W4[j*2 + 0] : 0.f;
            w4b[4*t+r] = (j < 50) ? W4[j*2 + 1] : 0.f;
        }
    const float b40 = b4[0], b41 = b4[1];

    // ---------------- L1 rank-2 correction weights (f32, rows k=10,11) ----------------
    float wc10[16], wc11[16];
#pragma unroll
    for (int t = 0; t < 4; ++t)
#pragma unroll
        for (int r = 0; r < 4; ++r){
            const int j = 16*t + 4*phi + r;
            wc10[4*t+r] = (j < 50) ? W1[10*50 + j] : 0.f;
            wc11[4*t+r] = (j < 50) ? W1[11*50 + j] : 0.f;
        }

    // ---------------- per-row state + per-lane X sources ----------------
    float ss[6];
#pragma unroll
    for (int i = 0; i < 6; ++i) ss[i] = state0[(size_t)rowg*6 + i];

    const float tg4 = target[(size_t)rowg*6 + 4];
    const float tg5 = target[(size_t)rowg*6 + 5];

    // per-phi target slices; phi2's slots 2,3 are handled by the correction -> 0
    float tgs0, tgs1, tgs2, tgs3;
    {
        const float* tg = target + (size_t)rowg*6;
        tgs0 = (phi==0) ? tg[0] : (phi==1) ? tg[4] : (phi==2) ? tg[2] : 0.f;
        tgs1 = (phi==0) ? tg[1] : (phi==1) ? tg[5] : (phi==2) ? tg[3] : 0.f;
        tgs2 = (phi==0) ? tg[2] : (phi==1) ? tg[0] : 0.f;
        tgs3 = (phi==0) ? tg[3] : (phi==1) ? tg[1] : 0.f;
    }
    float a0, a1, a2, a3;
    {
        const float* ps0 = pstate0 + (size_t)rowg*6;
        a0 = (phi==0) ? ps0[0] : (phi==1) ? ps0[4] : (phi==2) ? ss[2] : 0.f;
        a1 = (phi==0) ? ps0[1] : (phi==1) ? ps0[5] : (phi==2) ? ss[3] : 0.f;
        a2 = (phi==0) ? ps0[2] : (phi==1) ? ss[0]  : 0.f;   // phi2 slot -> deferred
        a3 = (phi==0) ? ps0[3] : (phi==1) ? ss[1]  : 0.f;   // phi2 slot -> deferred
    }
    float cv = ss[4], cvw = ss[5];   // pending rank-2 inputs (raw v,w sources)

    const float DT  = 0.05f;
    const float PI4 = 0.78539816339744830962f;
    const floatx4 z4 = {0.f,0.f,0.f,0.f};
    const uint32_t ONE_H = 0x00003C00u;

    float* uout = out + (size_t)rowg * 2;
    float* sout = out + (size_t)SEQ_LEN * BATCH * 2 + (size_t)rowg * 6;

    half8 H0a, H0b;

#define SPLITH(HA,HB,PK0,PK1) do{                                      \
        PK0 = pkh((HA),(HB));                                          \
        float _a = h16lo(PK0), _b = h16hi(PK0);                        \
        PK1 = pkh((HA)-_a, (HB)-_b);                                   \
    }while(0)

#define BUILD_F1(F) do{                                                \
        float xs0 = a0 - tgs0, xs1 = a1 - tgs1;                        \
        float xs2 = a2 - tgs2, xs3 = a3 - tgs3;                        \
        uint32_t pH01,pL01,pH23,pL23;                                  \
        SPLITH(xs0,xs1,pH01,pL01);                                     \
        SPLITH(xs2,xs3,pH23,pL23);                                     \
        uint4v f1;                                                     \
        f1[0] = (phi==3) ? ONE_H : pH01;                               \
        f1[1] = pH23;                                                  \
        f1[2] = pL01;                                                  \
        f1[3] = pL23;                                                  \
        F = ashfrag(f1);                                               \
    }while(0)

#define MKH(cc0,cc1,cc2,cc3) do{                                                   \
        uint4v u0a, u0b;                                                           \
        u0a[0] = pkh_rne(fmaxf(cc0[0],0.f), fmaxf(cc0[1],0.f));                    \
        u0a[1] = pkh_rne(fmaxf(cc0[2],0.f), fmaxf(cc0[3],0.f));                    \
        u0a[2] = pkh_rne(fmaxf(cc1[0],0.f), fmaxf(cc1[1],0.f));                    \
        u0a[3] = pkh_rne(fmaxf(cc1[2],0.f), fmaxf(cc1[3],0.f));                    \
        u0b[0] = pkh_rne(fmaxf(cc2[0],0.f), fmaxf(cc2[1],0.f));                    \
        u0b[1] = pkh_rne(fmaxf(cc2[2],0.f), fmaxf(cc2[3],0.f));                    \
        u0b[2] = pkh_rne(fmaxf(cc3[0],0.f), fmaxf(cc3[1],0.f));                    \
        u0b[3] = pkh_rne(fmaxf(cc3[2],0.f), fmaxf(cc3[3],0.f));                    \
        if (phi == 0) u0b[3] = ONE_H;     /* h[50]=1, h[51]=0 */                   \
        H0a = ashfrag(u0a); H0b = ashfrag(u0b);                                    \
    }while(0)

#define HID_RR(A)                                                                            \
        c0=MFMA_H(A[0][0][0],H0a,z4); c1=MFMA_H(A[0][1][0],H0a,z4); c2=MFMA_H(A[0][2][0],H0a,z4); c3=MFMA_H(A[0][3][0],H0a,z4); \
        c0=MFMA_H(A[0][0][1],H0b,c0); c1=MFMA_H(A[0][1][1],H0b,c1); c2=MFMA_H(A[0][2][1],H0b,c2); c3=MFMA_H(A[0][3][1],H0b,c3); \
        c0=MFMA_H(A[1][0][0],H0a,c0); c1=MFMA_H(A[1][1][0],H0a,c1); c2=MFMA_H(A[1][2][0],H0a,c2); c3=MFMA_H(A[1][3][0],H0a,c3); \
        c0=MFMA_H(A[1][0][1],H0b,c0); c1=MFMA_H(A[1][1][1],H0b,c1); c2=MFMA_H(A[1][2][1],H0b,c2); c3=MFMA_H(A[1][3][1],H0b,c3);

#define L4ACC(CT,T) do{                                                   \
        _Pragma("unroll")                                                 \
        for (int r = 0; r < 4; ++r){                                      \
            float hv = fmaxf(CT[r], 0.f);                                 \
            z0p = fmaf(hv, w4a[4*(T)+r], z0p);                            \
            z1p = fmaf(hv, w4b[4*(T)+r], z1p);                            \
        }                                                                 \
    }while(0)

#define CORR(CT,T) do{                                                    \
        _Pragma("unroll")                                                 \
        for (int r = 0; r < 4; ++r)                                       \
            CT[r] = fmaf(wc10[4*(T)+r], xv, fmaf(wc11[4*(T)+r], xw, CT[r])); \
    }while(0)

    // ---------------- prologue: F1(0) partial + L1 MFMAs ----------------
    half8 F1;
    BUILD_F1(F1);
    floatx4 d0, d1, d2, d3;
    d0=MFMA_H(P1[0],F1,z4); d1=MFMA_H(P1[1],F1,z4); d2=MFMA_H(P1[2],F1,z4); d3=MFMA_H(P1[3],F1,z4);
    d0=MFMA_H(Q1[0],F1,d0); d1=MFMA_H(Q1[1],F1,d1); d2=MFMA_H(Q1[2],F1,d2); d3=MFMA_H(Q1[3],F1,d3);

    for (int t = 0; t < SEQ_LEN; ++t){
        // ---- adopt prefetched L1 output, apply exact rank-2 correction ----
        floatx4 c0 = d0, c1 = d1, c2 = d2, c3 = d3;
        {
            float xv = cv - tg4, xw = cvw - tg5;
            CORR(c0,0); CORR(c1,1); CORR(c2,2); CORR(c3,3);
        }
        MKH(c0,c1,c2,c3);

        // ---- layer 2 (16 MFMAs) ----
        HID_RR(A2)
        MKH(c0,c1,c2,c3);

        // ---- layer 3 (16 MFMAs) ----
        HID_RR(A3)

        // ---- dynamics part 1 (ss-only; overlaps L3 in-flight) ----
        float th = ss[5]*DT, t2 = th*th;
        float sw = th * fmaf(t2, fmaf(t2, 8.3333333333e-3f, -1.6666666667e-1f), 1.0f);
        float cw = fmaf(t2, fmaf(t2, fmaf(t2, -1.3888888889e-3f, 4.1666666667e-2f), -0.5f), 1.0f);
        float nx = fmaf(ss[4]*ss[2], DT, ss[0]);
        float ny = fmaf(ss[4]*ss[3], DT, ss[1]);
        float nc = ss[2]*cw - ss[3]*sw;
        float ns = fmaf(ss[3], cw, nc*sw);           // uses c_new

        // ---- build F1(t+1) partial and issue next L1 (overlaps the tail) ----
        a0 = (phi==0) ? ss[0] : (phi==1) ? ss[4] : (phi==2) ? nc : a0;
        a1 = (phi==0) ? ss[1] : (phi==1) ? ss[5] : (phi==2) ? ns : a1;
        a2 = (phi==0) ? ss[2] : (phi==1) ? nx    : a2;   // phi2 stays 0
        a3 = (phi==0) ? ss[3] : (phi==1) ? ny    : a3;   // phi2 stays 0
        BUILD_F1(F1);
        d0=MFMA_H(P1[0],F1,z4); d1=MFMA_H(P1[1],F1,z4); d2=MFMA_H(P1[2],F1,z4); d3=MFMA_H(P1[3],F1,z4);
        d0=MFMA_H(Q1[0],F1,d0); d1=MFMA_H(Q1[1],F1,d1); d2=MFMA_H(Q1[2],F1,d2); d3=MFMA_H(Q1[3],F1,d3);

        // ---- layer 4: per-lane f32 partials + permlane reduce ----
        float z0p = 0.f, z1p = 0.f;
        L4ACC(c0,0); L4ACC(c1,1); L4ACC(c2,2); L4ACC(c3,3);
        z0p = xor16_sum(z0p); z1p = xor16_sum(z1p);
        z0p = xor32_sum(z0p); z1p = xor32_sum(z1p);
        float zz0 = z0p + b40;
        float zz1 = z1p + b41;

        // u = 0.5*tanh(z) = 0.5 - 1/(exp(2z)+1)
        float u0 = 0.5f - __builtin_amdgcn_rcpf(__expf(2.0f*zz0) + 1.0f);
        float u1 = 0.5f - __builtin_amdgcn_rcpf(__expf(2.0f*zz1) + 1.0f);

        float nv = fminf(fmaxf(fmaf(u0, DT, ss[4]), -0.1f), 0.3f);
        float nw = fminf(fmaxf(fmaf(u1, DT, ss[5]), -PI4), PI4);

        // ---- verified store scheme: one lane per row writes everything ----
        if (phi == 0){
            float2v uv  = {u0, u1};
            *(float2v*)uout = uv;
            float2v s01 = {nx, ny}, s23 = {nc, ns}, s45 = {nv, nw};
            *(float2v*)(sout    ) = s01;
            *(float2v*)(sout + 2) = s23;
            *(float2v*)(sout + 4) = s45;
        }
        uout += (size_t)BATCH * 2;
        sout += (size_t)BATCH * 6;

        cv = nv; cvw = nw;
        ss[0]=nx; ss[1]=ny; ss[2]=nc; ss[3]=ns; ss[4]=nv; ss[5]=nw;
    }
#undef MKH
#undef SPLITH
#undef BUILD_F1
#undef HID_RR
#undef L4ACC
#undef CORR
}

extern "C" void kernel_launch(void* const* d_in, const int* in_sizes, int n_in,
                              void* d_out, int out_size, void* d_ws, size_t ws_size,
                              hipStream_t stream)
{
    const float* state  = (const float*)d_in[0];
    const float* pstate = (const float*)d_in[1];
    const float* target = (const float*)d_in[2];
    const float* W1 = (const float*)d_in[3];
    const float* b1 = (const float*)d_in[4];
    const float* W2 = (const float*)d_in[5];
    const float* b2 = (const float*)d_in[6];
    const float* W3 = (const float*)d_in[7];
    const float* b3 = (const float*)d_in[8];
    const float* W4 = (const float*)d_in[9];
    const float* b4 = (const float*)d_in[10];
    float* out = (float*)d_out;

    dim3 grid(BATCH/16), block(64);
    mbrl_mfma<<<grid, block, 0, stream>>>(state, pstate, target,
                                          W1,b1,W2,b2,W3,b3,W4,b4, out);
}